// Round 2
// baseline (9590.514 us; speedup 1.0000x reference)
//
#include <hip/hip_runtime.h>
#include <math.h>

#define E_ 4
#define B_ 16
#define S_ 224
#define P_ 16
#define D_ 384
#define H_ 6
#define HD_ 64
#define L_ 12
#define FF_ 1536
#define NC_ 10
#define NP_ 196
#define T_ 197
#define GATE_K (3 * S_ * S_)  // 150528

// ---------------- gate: logits = x_flat @ gate_w + gate_b ; idx = argmax ----------------
__global__ void gate_kernel(const float* __restrict__ x, const float* __restrict__ gw,
                            const float* __restrict__ gb, int* __restrict__ idx) {
  int b = blockIdx.x;
  int tid = threadIdx.x;
  const float* xb = x + (size_t)b * GATE_K;
  const float4* gw4 = (const float4*)gw;  // rows of 4 floats, 16B aligned
  float4 acc = make_float4(0.f, 0.f, 0.f, 0.f);
  for (int i = tid; i < GATE_K; i += 256) {
    float xv = xb[i];
    float4 w = gw4[i];
    acc.x += xv * w.x; acc.y += xv * w.y; acc.z += xv * w.z; acc.w += xv * w.w;
  }
  __shared__ float4 red[256];
  red[tid] = acc;
  __syncthreads();
  for (int off = 128; off > 0; off >>= 1) {
    if (tid < off) {
      float4 o = red[tid + off];
      red[tid].x += o.x; red[tid].y += o.y; red[tid].z += o.z; red[tid].w += o.w;
    }
    __syncthreads();
  }
  if (tid == 0) {
    float v[4] = {red[0].x + gb[0], red[0].y + gb[1], red[0].z + gb[2], red[0].w + gb[3]};
    int best = 0;
    for (int e = 1; e < 4; ++e) if (v[e] > v[best]) best = e;  // first-max like jnp.argmax
    idx[b] = best;
  }
}

// ---------------- cls row: t[b][0] = cls[e] + pos[e][0] ----------------
__global__ void cls_kernel(const float* __restrict__ cls, const float* __restrict__ pos,
                           const int* __restrict__ idx, float* __restrict__ t) {
  int b = blockIdx.x;
  int d = threadIdx.x;
  int e = idx[b];
  t[((size_t)b * T_) * D_ + d] = cls[e * D_ + d] + pos[((size_t)e * T_) * D_ + d];
}

// ---------------- patch embed ----------------
__global__ void patch_kernel(const float* __restrict__ x, const float* __restrict__ pw,
                             const float* __restrict__ pb, const float* __restrict__ pos,
                             const int* __restrict__ idx, float* __restrict__ t) {
  int b = blockIdx.y;
  int e = idx[b];
  int m0 = blockIdx.x * 14;
  int tid = threadIdx.x;  // 384 threads
  __shared__ float xin[14][768];
  for (int jj = tid; jj < 14 * 768; jj += 384) {
    int r = jj / 768, j = jj - r * 768;
    int m = m0 + r;
    int pr = m / 14, pc = m - pr * 14;
    int c = j >> 8, y = (j >> 4) & 15, xx = j & 15;
    xin[r][j] = x[(((size_t)b * 3 + c) * S_ + (pr * 16 + y)) * S_ + pc * 16 + xx];
  }
  __syncthreads();
  int d = tid;
  float acc[14];
#pragma unroll
  for (int r = 0; r < 14; ++r) acc[r] = 0.f;
  const float* pwe = pw + (size_t)e * 768 * D_;
  for (int k = 0; k < 768; ++k) {
    float wv = pwe[(size_t)k * D_ + d];
#pragma unroll
    for (int r = 0; r < 14; ++r) acc[r] += xin[r][k] * wv;
  }
  float bias = pb[e * D_ + d];
#pragma unroll
  for (int r = 0; r < 14; ++r) {
    int row = 1 + m0 + r;
    t[((size_t)b * T_ + row) * D_ + d] = acc[r] + bias + pos[((size_t)e * T_ + row) * D_ + d];
  }
}

// ---------------- layernorm ----------------
__global__ void ln_kernel(const float* __restrict__ in, float* __restrict__ out,
                          const float* __restrict__ w, const float* __restrict__ bc,
                          const int* __restrict__ idx, int l) {
  int b = blockIdx.y;
  int row = blockIdx.x * 4 + (threadIdx.x >> 6);
  if (row >= T_) return;
  int lane = threadIdx.x & 63;
  int e = idx[b];
  const float* rp = in + ((size_t)b * T_ + row) * D_;
  float v[6];
  float s = 0.f;
#pragma unroll
  for (int j = 0; j < 6; ++j) { v[j] = rp[lane + j * 64]; s += v[j]; }
#pragma unroll
  for (int off = 1; off < 64; off <<= 1) s += __shfl_xor(s, off);
  float mean = s * (1.f / 384.f);
  float sq = 0.f;
#pragma unroll
  for (int j = 0; j < 6; ++j) { float dd = v[j] - mean; sq += dd * dd; }
#pragma unroll
  for (int off = 1; off < 64; off <<= 1) sq += __shfl_xor(sq, off);
  float rs = rsqrtf(sq * (1.f / 384.f) + 1e-6f);
  const float* wrow = w + ((size_t)e * L_ + l) * D_;
  const float* brow = bc + ((size_t)e * L_ + l) * D_;
  float* op = out + ((size_t)b * T_ + row) * D_;
#pragma unroll
  for (int j = 0; j < 6; ++j) {
    int d = lane + j * 64;
    op[d] = (v[j] - mean) * rs * wrow[d] + brow[d];
  }
}

// ---------------- tiled fp32 GEMM ----------------
template <int EPI>
__global__ void gemm_kernel(const float* __restrict__ A, const float* __restrict__ W,
                            const float* __restrict__ bias, float* __restrict__ Out,
                            const int* __restrict__ idx, int l, int K, int N) {
  int b = blockIdx.z;
  int e = idx[b];
  int n0 = blockIdx.x * 64;
  int m0 = blockIdx.y * 64;
  int tid = threadIdx.x;
  const float* Ab = A + (size_t)b * T_ * K;
  const float* Wb = W + ((size_t)e * L_ + l) * (size_t)K * N;
  __shared__ float As[16][64];
  __shared__ float Bs[16][64];
  float acc[4][4] = {};
  int tx = tid & 15, ty = tid >> 4;
  int am = tid >> 2, akq = (tid & 3) * 4;
  int bk = tid >> 4, bnq = (tid & 15) * 4;
  for (int k0 = 0; k0 < K; k0 += 16) {
    int row = m0 + am;
    float4 av = make_float4(0.f, 0.f, 0.f, 0.f);
    if (row < T_) av = *(const float4*)(Ab + (size_t)row * K + k0 + akq);
    As[akq + 0][am] = av.x;
    As[akq + 1][am] = av.y;
    As[akq + 2][am] = av.z;
    As[akq + 3][am] = av.w;
    float4 bv = *(const float4*)(Wb + (size_t)(k0 + bk) * N + n0 + bnq);
    *(float4*)&Bs[bk][bnq] = bv;
    __syncthreads();
#pragma unroll
    for (int k = 0; k < 16; ++k) {
      float4 a4 = *(const float4*)&As[k][ty * 4];
      float4 b4 = *(const float4*)&Bs[k][tx * 4];
      float ar[4] = {a4.x, a4.y, a4.z, a4.w};
      float br[4] = {b4.x, b4.y, b4.z, b4.w};
#pragma unroll
      for (int r = 0; r < 4; ++r)
#pragma unroll
        for (int c = 0; c < 4; ++c) acc[r][c] += ar[r] * br[c];
    }
    __syncthreads();
  }
  const float* brow = bias + ((size_t)e * L_ + l) * N + n0;
#pragma unroll
  for (int r = 0; r < 4; ++r) {
    int row = m0 + ty * 4 + r;
    if (row >= T_) continue;
    float* orow = Out + ((size_t)b * T_ + row) * N + n0;
#pragma unroll
    for (int c = 0; c < 4; ++c) {
      int col = tx * 4 + c;
      float val = acc[r][c] + brow[col];
      if (EPI == 1) val += orow[col];
      if (EPI == 2) val = 0.5f * val * (1.f + erff(val * 0.70710678118654752f));
      orow[col] = val;
    }
  }
}

// ---------------- attention v2: LDS-staged, register-blocked ----------------
// Block: (qtile of 32 rows, head, batch); 256 threads.
// Phase 1: Sc[32][k] = Q(32x64) @ K^T, k-tiled by 64 (K staged transposed in LDS).
// Phase 2: softmax rows (8 lanes/row).
// Phase 3: O = P @ V, k-tiled by 64 (V staged row-major in LDS).
__global__ void attn_kernel(const float* __restrict__ qkv, float* __restrict__ o) {
  int b = blockIdx.z, h = blockIdx.y, qt = blockIdx.x;
  int q0 = qt * 32;
  int tid = threadIdx.x;  // 256
  __shared__ float Qt[64][34];   // [d][q], transposed Q tile
  __shared__ float KV[64][68];   // phase1: Kt[d][k]; phase3: Vs[k][d] (stride 68 keeps f4 align)
  __shared__ float Sc[32][200];
  const float* base = qkv + (size_t)b * T_ * (3 * D_);
  int ty = tid >> 4, tx = tid & 15;

  // stage Q transposed: 32 rows x 16 float4 = 512 items, 2 per thread
#pragma unroll
  for (int i = 0; i < 2; ++i) {
    int item = tid + i * 256;
    int qi = item >> 4, dq = (item & 15) * 4;
    int row = q0 + qi;
    float4 qv = make_float4(0.f, 0.f, 0.f, 0.f);
    if (row < T_) qv = *(const float4*)(base + (size_t)row * (3 * D_) + h * HD_ + dq);
    Qt[dq + 0][qi] = qv.x;
    Qt[dq + 1][qi] = qv.y;
    Qt[dq + 2][qi] = qv.z;
    Qt[dq + 3][qi] = qv.w;
  }

  // ---- phase 1: scores ----
  for (int kt = 0; kt < 4; ++kt) {
    int kb = kt * 64;
    __syncthreads();  // KV free (prev compute done / Q-stage irrelevant)
    // stage K-tile transposed: 64 rows x 16 float4 = 1024 items, 4 per thread
#pragma unroll
    for (int i = 0; i < 4; ++i) {
      int item = tid + i * 256;
      int kk = item >> 4, dq = (item & 15) * 4;
      int krow = kb + kk;
      float4 kv = make_float4(0.f, 0.f, 0.f, 0.f);
      if (krow < T_) kv = *(const float4*)(base + (size_t)krow * (3 * D_) + D_ + h * HD_ + dq);
      KV[dq + 0][kk] = kv.x;
      KV[dq + 1][kk] = kv.y;
      KV[dq + 2][kk] = kv.z;
      KV[dq + 3][kk] = kv.w;
    }
    __syncthreads();
    float acc[2][4] = {};
#pragma unroll 16
    for (int d = 0; d < 64; ++d) {
      float a0 = Qt[d][ty * 2 + 0];
      float a1 = Qt[d][ty * 2 + 1];
      float4 bb = *(const float4*)&KV[d][tx * 4];
      acc[0][0] += a0 * bb.x; acc[0][1] += a0 * bb.y; acc[0][2] += a0 * bb.z; acc[0][3] += a0 * bb.w;
      acc[1][0] += a1 * bb.x; acc[1][1] += a1 * bb.y; acc[1][2] += a1 * bb.z; acc[1][3] += a1 * bb.w;
    }
#pragma unroll
    for (int r = 0; r < 2; ++r)
#pragma unroll
      for (int c = 0; c < 4; ++c) {
        int kc = kb + tx * 4 + c;
        if (kc < T_) Sc[ty * 2 + r][kc] = acc[r][c] * 0.125f;
      }
  }
  __syncthreads();

  // ---- phase 2: softmax (8 lanes per row) ----
  {
    int r = tid >> 3, l8 = tid & 7;
    float mx = -1e30f;
    for (int k = l8; k < T_; k += 8) mx = fmaxf(mx, Sc[r][k]);
#pragma unroll
    for (int off = 4; off > 0; off >>= 1) mx = fmaxf(mx, __shfl_xor(mx, off, 8));
    float sum = 0.f;
    for (int k = l8; k < T_; k += 8) {
      float p = expf(Sc[r][k] - mx);
      Sc[r][k] = p;
      sum += p;
    }
#pragma unroll
    for (int off = 4; off > 0; off >>= 1) sum += __shfl_xor(sum, off, 8);
    float inv = 1.f / sum;
    for (int k = l8; k < T_; k += 8) Sc[r][k] *= inv;
  }

  // ---- phase 3: O = P @ V ----
  float out[2][4] = {};
  for (int kt = 0; kt < 4; ++kt) {
    int kb = kt * 64;
    int kn = T_ - kb; if (kn > 64) kn = 64;
    __syncthreads();
    // stage V-tile row-major: KV[kk][d]
#pragma unroll
    for (int i = 0; i < 4; ++i) {
      int item = tid + i * 256;
      int kk = item >> 4, dq = (item & 15) * 4;
      int krow = kb + kk;
      float4 vv = make_float4(0.f, 0.f, 0.f, 0.f);
      if (krow < T_) vv = *(const float4*)(base + (size_t)krow * (3 * D_) + 2 * D_ + h * HD_ + dq);
      *(float4*)&KV[kk][dq] = vv;
    }
    __syncthreads();
    for (int kk = 0; kk < kn; ++kk) {
      float p0 = Sc[ty * 2 + 0][kb + kk];
      float p1 = Sc[ty * 2 + 1][kb + kk];
      float4 vv = *(const float4*)&KV[kk][tx * 4];
      out[0][0] += p0 * vv.x; out[0][1] += p0 * vv.y; out[0][2] += p0 * vv.z; out[0][3] += p0 * vv.w;
      out[1][0] += p1 * vv.x; out[1][1] += p1 * vv.y; out[1][2] += p1 * vv.z; out[1][3] += p1 * vv.w;
    }
  }
#pragma unroll
  for (int r = 0; r < 2; ++r) {
    int row = q0 + ty * 2 + r;
    if (row < T_) {
      float* op = o + ((size_t)b * T_ + row) * D_ + h * HD_ + tx * 4;
      op[0] = out[r][0]; op[1] = out[r][1]; op[2] = out[r][2]; op[3] = out[r][3];
    }
  }
}

// ---------------- final LN(row 0) + head ----------------
__global__ void head_kernel(const float* __restrict__ t, const float* __restrict__ nw,
                            const float* __restrict__ nb, const float* __restrict__ hw,
                            const float* __restrict__ hb, const int* __restrict__ idx,
                            float* __restrict__ out) {
  int b = blockIdx.x;
  int e = idx[b];
  int lane = threadIdx.x;  // 64
  const float* rp = t + (size_t)b * T_ * D_;
  float v[6];
  float s = 0.f;
#pragma unroll
  for (int j = 0; j < 6; ++j) { v[j] = rp[lane + j * 64]; s += v[j]; }
#pragma unroll
  for (int off = 1; off < 64; off <<= 1) s += __shfl_xor(s, off);
  float mean = s * (1.f / 384.f);
  float sq = 0.f;
#pragma unroll
  for (int j = 0; j < 6; ++j) { float dd = v[j] - mean; sq += dd * dd; }
#pragma unroll
  for (int off = 1; off < 64; off <<= 1) sq += __shfl_xor(sq, off);
  float rs = rsqrtf(sq * (1.f / 384.f) + 1e-6f);
  __shared__ float ln[D_];
#pragma unroll
  for (int j = 0; j < 6; ++j) {
    int d = lane + j * 64;
    ln[d] = (v[j] - mean) * rs * nw[e * D_ + d] + nb[e * D_ + d];
  }
  __syncthreads();
  if (lane < NC_) {
    float acc = hb[e * NC_ + lane];
    for (int d = 0; d < D_; ++d) acc += ln[d] * hw[((size_t)e * D_ + d) * NC_ + lane];
    out[b * NC_ + lane] = acc;
  }
}

extern "C" void kernel_launch(void* const* d_in, const int* in_sizes, int n_in,
                              void* d_out, int out_size, void* d_ws, size_t ws_size,
                              hipStream_t stream) {
  const float* x      = (const float*)d_in[0];
  const float* gate_w = (const float*)d_in[1];
  const float* gate_b = (const float*)d_in[2];
  const float* patch_w = (const float*)d_in[3];
  const float* patch_b = (const float*)d_in[4];
  const float* cls    = (const float*)d_in[5];
  const float* pos    = (const float*)d_in[6];
  const float* ln1_w  = (const float*)d_in[7];
  const float* ln1_b  = (const float*)d_in[8];
  const float* qkv_w  = (const float*)d_in[9];
  const float* qkv_b  = (const float*)d_in[10];
  const float* proj_w = (const float*)d_in[11];
  const float* proj_b = (const float*)d_in[12];
  const float* ln2_w  = (const float*)d_in[13];
  const float* ln2_b  = (const float*)d_in[14];
  const float* fc1_w  = (const float*)d_in[15];
  const float* fc1_b  = (const float*)d_in[16];
  const float* fc2_w  = (const float*)d_in[17];
  const float* fc2_b  = (const float*)d_in[18];
  const float* norm_w = (const float*)d_in[19];
  const float* norm_b = (const float*)d_in[20];
  const float* head_w = (const float*)d_in[21];
  const float* head_b = (const float*)d_in[22];

  float* ws = (float*)d_ws;
  int* idx   = (int*)ws;
  float* t   = ws + 64;
  float* h   = t + (size_t)B_ * T_ * D_;
  float* qkv = h + (size_t)B_ * T_ * D_;
  float* o   = qkv + (size_t)B_ * T_ * 3 * D_;
  float* u   = o + (size_t)B_ * T_ * D_;

  gate_kernel<<<B_, 256, 0, stream>>>(x, gate_w, gate_b, idx);
  cls_kernel<<<B_, D_, 0, stream>>>(cls, pos, idx, t);
  patch_kernel<<<dim3(14, B_), D_, 0, stream>>>(x, patch_w, patch_b, pos, idx, t);
  for (int l = 0; l < L_; ++l) {
    ln_kernel<<<dim3(50, B_), 256, 0, stream>>>(t, h, ln1_w, ln1_b, idx, l);
    gemm_kernel<0><<<dim3(18, 4, B_), 256, 0, stream>>>(h, qkv_w, qkv_b, qkv, idx, l, D_, 3 * D_);
    attn_kernel<<<dim3(7, H_, B_), 256, 0, stream>>>(qkv, o);
    gemm_kernel<1><<<dim3(6, 4, B_), 256, 0, stream>>>(o, proj_w, proj_b, t, idx, l, D_, D_);
    ln_kernel<<<dim3(50, B_), 256, 0, stream>>>(t, h, ln2_w, ln2_b, idx, l);
    gemm_kernel<2><<<dim3(24, 4, B_), 256, 0, stream>>>(h, fc1_w, fc1_b, u, idx, l, D_, FF_);
    gemm_kernel<1><<<dim3(6, 4, B_), 256, 0, stream>>>(u, fc2_w, fc2_b, t, idx, l, FF_, D_);
  }
  head_kernel<<<B_, 64, 0, stream>>>(t, norm_w, norm_b, head_w, head_b, idx, (float*)d_out);
}

// Round 3
// 7761.499 us; speedup vs baseline: 1.2357x; 1.2357x over previous
//
#include <hip/hip_runtime.h>
#include <math.h>

#define E_ 4
#define B_ 16
#define S_ 224
#define P_ 16
#define D_ 384
#define H_ 6
#define HD_ 64
#define L_ 12
#define FF_ 1536
#define NC_ 10
#define NP_ 196
#define T_ 197
#define GATE_K (3 * S_ * S_)  // 150528

typedef __attribute__((ext_vector_type(8))) short bf16x8;
typedef __attribute__((ext_vector_type(4))) float f32x4;

__device__ inline unsigned short f2bf(float f) {
  union { float f; unsigned u; } v; v.f = f;
  unsigned r = v.u + 0x7FFFu + ((v.u >> 16) & 1u);  // RNE
  return (unsigned short)(r >> 16);
}

// ---------------- gate ----------------
__global__ void gate_kernel(const float* __restrict__ x, const float* __restrict__ gw,
                            const float* __restrict__ gb, int* __restrict__ idx) {
  int b = blockIdx.x;
  int tid = threadIdx.x;
  const float* xb = x + (size_t)b * GATE_K;
  const float4* gw4 = (const float4*)gw;
  float4 acc = make_float4(0.f, 0.f, 0.f, 0.f);
  for (int i = tid; i < GATE_K; i += 256) {
    float xv = xb[i];
    float4 w = gw4[i];
    acc.x += xv * w.x; acc.y += xv * w.y; acc.z += xv * w.z; acc.w += xv * w.w;
  }
  __shared__ float4 red[256];
  red[tid] = acc;
  __syncthreads();
  for (int off = 128; off > 0; off >>= 1) {
    if (tid < off) {
      float4 o = red[tid + off];
      red[tid].x += o.x; red[tid].y += o.y; red[tid].z += o.z; red[tid].w += o.w;
    }
    __syncthreads();
  }
  if (tid == 0) {
    float v[4] = {red[0].x + gb[0], red[0].y + gb[1], red[0].z + gb[2], red[0].w + gb[3]};
    int best = 0;
    for (int e = 1; e < 4; ++e) if (v[e] > v[best]) best = e;
    idx[b] = best;
  }
}

// ---------------- cls row ----------------
__global__ void cls_kernel(const float* __restrict__ cls, const float* __restrict__ pos,
                           const int* __restrict__ idx, float* __restrict__ t) {
  int b = blockIdx.x;
  int d = threadIdx.x;
  int e = idx[b];
  t[((size_t)b * T_) * D_ + d] = cls[e * D_ + d] + pos[((size_t)e * T_) * D_ + d];
}

// ---------------- patch embed ----------------
__global__ void patch_kernel(const float* __restrict__ x, const float* __restrict__ pw,
                             const float* __restrict__ pb, const float* __restrict__ pos,
                             const int* __restrict__ idx, float* __restrict__ t) {
  int b = blockIdx.y;
  int e = idx[b];
  int m0 = blockIdx.x * 14;
  int tid = threadIdx.x;  // 384
  __shared__ float xin[14][768];
  for (int jj = tid; jj < 14 * 768; jj += 384) {
    int r = jj / 768, j = jj - r * 768;
    int m = m0 + r;
    int pr = m / 14, pc = m - pr * 14;
    int c = j >> 8, y = (j >> 4) & 15, xx = j & 15;
    xin[r][j] = x[(((size_t)b * 3 + c) * S_ + (pr * 16 + y)) * S_ + pc * 16 + xx];
  }
  __syncthreads();
  int d = tid;
  float acc[14];
#pragma unroll
  for (int r = 0; r < 14; ++r) acc[r] = 0.f;
  const float* pwe = pw + (size_t)e * 768 * D_;
  for (int k = 0; k < 768; ++k) {
    float wv = pwe[(size_t)k * D_ + d];
#pragma unroll
    for (int r = 0; r < 14; ++r) acc[r] += xin[r][k] * wv;
  }
  float bias = pb[e * D_ + d];
#pragma unroll
  for (int r = 0; r < 14; ++r) {
    int row = 1 + m0 + r;
    t[((size_t)b * T_ + row) * D_ + d] = acc[r] + bias + pos[((size_t)e * T_ + row) * D_ + d];
  }
}

// ---------------- layernorm -> bf16 out ----------------
__global__ void ln_kernel(const float* __restrict__ in, unsigned short* __restrict__ out,
                          const float* __restrict__ w, const float* __restrict__ bc,
                          const int* __restrict__ idx, int l) {
  int b = blockIdx.y;
  int row = blockIdx.x * 4 + (threadIdx.x >> 6);
  if (row >= T_) return;
  int lane = threadIdx.x & 63;
  int e = idx[b];
  const float* rp = in + ((size_t)b * T_ + row) * D_;
  float v[6];
  float s = 0.f;
#pragma unroll
  for (int j = 0; j < 6; ++j) { v[j] = rp[lane + j * 64]; s += v[j]; }
#pragma unroll
  for (int off = 1; off < 64; off <<= 1) s += __shfl_xor(s, off);
  float mean = s * (1.f / 384.f);
  float sq = 0.f;
#pragma unroll
  for (int j = 0; j < 6; ++j) { float dd = v[j] - mean; sq += dd * dd; }
#pragma unroll
  for (int off = 1; off < 64; off <<= 1) sq += __shfl_xor(sq, off);
  float rs = rsqrtf(sq * (1.f / 384.f) + 1e-6f);
  const float* wrow = w + ((size_t)e * L_ + l) * D_;
  const float* brow = bc + ((size_t)e * L_ + l) * D_;
  unsigned short* op = out + ((size_t)b * T_ + row) * D_;
#pragma unroll
  for (int j = 0; j < 6; ++j) {
    int d = lane + j * 64;
    op[d] = f2bf((v[j] - mean) * rs * wrow[d] + brow[d]);
  }
}

// ---------------- per-layer weight transpose: W[K][N] fp32 -> WT[N][K] bf16 ----------------
__global__ __launch_bounds__(256) void wtrans_kernel(
    const float* __restrict__ qw, const float* __restrict__ pw,
    const float* __restrict__ f1, const float* __restrict__ f2,
    unsigned short* __restrict__ tq, unsigned short* __restrict__ tp,
    unsigned short* __restrict__ t1, unsigned short* __restrict__ t2, int l) {
  int e = blockIdx.y;
  int r = blockIdx.x;  // 0..1727
  const float* src; unsigned short* dst; int K, N, kt, nt;
  if (r < 432) {        // qkv: 384x1152, 12x36 tiles
    K = 384; N = 1152;
    src = qw + (size_t)(e * L_ + l) * K * N; dst = tq + (size_t)e * K * N;
    kt = r / 36; nt = r % 36;
  } else if (r < 576) { // proj: 384x384, 12x12
    r -= 432; K = 384; N = 384;
    src = pw + (size_t)(e * L_ + l) * K * N; dst = tp + (size_t)e * K * N;
    kt = r / 12; nt = r % 12;
  } else if (r < 1152) {// fc1: 384x1536, 12x48
    r -= 576; K = 384; N = 1536;
    src = f1 + (size_t)(e * L_ + l) * K * N; dst = t1 + (size_t)e * K * N;
    kt = r / 48; nt = r % 48;
  } else {              // fc2: 1536x384, 48x12
    r -= 1152; K = 1536; N = 384;
    src = f2 + (size_t)(e * L_ + l) * K * N; dst = t2 + (size_t)e * K * N;
    kt = r / 12; nt = r % 12;
  }
  int k0 = kt * 32, n0 = nt * 32;
  __shared__ float tile[32][33];
  int t = threadIdx.x;
  int rr = t >> 3, c4 = (t & 7) * 4;
  float4 v = *(const float4*)(src + (size_t)(k0 + rr) * N + n0 + c4);
  tile[rr][c4 + 0] = v.x; tile[rr][c4 + 1] = v.y;
  tile[rr][c4 + 2] = v.z; tile[rr][c4 + 3] = v.w;
  __syncthreads();
  int n = t >> 3, k4 = (t & 7) * 4;
  ushort4 o;
  o.x = f2bf(tile[k4 + 0][n]); o.y = f2bf(tile[k4 + 1][n]);
  o.z = f2bf(tile[k4 + 2][n]); o.w = f2bf(tile[k4 + 3][n]);
  *(ushort4*)(dst + (size_t)(n0 + n) * K + k0 + k4) = o;
}

// ---------------- MFMA bf16 GEMM: Out[b] = A[b](bf16) @ WT[e]^T + bias ----------------
// A: [B][T][K] bf16. WT: [E][N][K] bf16 (current layer). 64x64 tile, BK=32, 4 waves (2x2).
// EPI: 0 = store fp32, 1 = fp32 residual add, 2 = GELU -> bf16 store.
template <int EPI>
__global__ __launch_bounds__(256, 4) void gemm_mfma(
    const unsigned short* __restrict__ A, const unsigned short* __restrict__ WT,
    const float* __restrict__ bias, void* __restrict__ Out,
    const int* __restrict__ idx, int l, int K, int N) {
  int b = blockIdx.z;
  int e = idx[b];
  int n0 = blockIdx.x * 64, m0 = blockIdx.y * 64;
  int tid = threadIdx.x;
  const unsigned short* Ab = A + (size_t)b * T_ * K;
  const unsigned short* Wb = WT + (size_t)e * N * K;
  __shared__ unsigned short Asl[4][64][8];  // [kgrp][row][j]
  __shared__ unsigned short Bsl[4][64][8];  // [kgrp][col][j]
  f32x4 acc[2][2];
#pragma unroll
  for (int i = 0; i < 2; ++i)
#pragma unroll
    for (int j = 0; j < 2; ++j) acc[i][j] = (f32x4){0.f, 0.f, 0.f, 0.f};
  int wid = tid >> 6, lane = tid & 63;
  int wm = (wid >> 1) * 32, wn = (wid & 1) * 32;
  int lrow = lane & 15, lk = lane >> 4;
  int ar = tid >> 2, akq = tid & 3;  // A stage: row, kgrp
  for (int k0 = 0; k0 < K; k0 += 32) {
    uint4 av = make_uint4(0, 0, 0, 0);
    if (m0 + ar < T_) av = *(const uint4*)(Ab + (size_t)(m0 + ar) * K + k0 + akq * 8);
    uint4 bv = *(const uint4*)(Wb + (size_t)(n0 + ar) * K + k0 + akq * 8);
    __syncthreads();
    *(uint4*)&Asl[akq][ar][0] = av;
    *(uint4*)&Bsl[akq][ar][0] = bv;
    __syncthreads();
    bf16x8 a0 = *(const bf16x8*)&Asl[lk][wm + lrow][0];
    bf16x8 a1 = *(const bf16x8*)&Asl[lk][wm + 16 + lrow][0];
    bf16x8 b0 = *(const bf16x8*)&Bsl[lk][wn + lrow][0];
    bf16x8 b1 = *(const bf16x8*)&Bsl[lk][wn + 16 + lrow][0];
    acc[0][0] = __builtin_amdgcn_mfma_f32_16x16x32_bf16(a0, b0, acc[0][0], 0, 0, 0);
    acc[0][1] = __builtin_amdgcn_mfma_f32_16x16x32_bf16(a0, b1, acc[0][1], 0, 0, 0);
    acc[1][0] = __builtin_amdgcn_mfma_f32_16x16x32_bf16(a1, b0, acc[1][0], 0, 0, 0);
    acc[1][1] = __builtin_amdgcn_mfma_f32_16x16x32_bf16(a1, b1, acc[1][1], 0, 0, 0);
  }
  const float* brow = bias + ((size_t)e * L_ + l) * N + n0;
#pragma unroll
  for (int fm = 0; fm < 2; ++fm)
#pragma unroll
    for (int fn = 0; fn < 2; ++fn) {
      int col = wn + fn * 16 + lrow;
      float bval = brow[col];
#pragma unroll
      for (int r = 0; r < 4; ++r) {
        int row = m0 + wm + fm * 16 + lk * 4 + r;
        if (row >= T_) continue;
        float val = acc[fm][fn][r] + bval;
        if (EPI == 0) {
          ((float*)Out)[((size_t)b * T_ + row) * N + n0 + col] = val;
        } else if (EPI == 1) {
          float* p = (float*)Out + ((size_t)b * T_ + row) * N + n0 + col;
          *p = *p + val;
        } else {
          val = 0.5f * val * (1.f + erff(val * 0.70710678118654752f));
          ((unsigned short*)Out)[((size_t)b * T_ + row) * N + n0 + col] = f2bf(val);
        }
      }
    }
}

// ---------------- attention (fp32 in, bf16 out) ----------------
__global__ __launch_bounds__(256, 2) void attn_kernel(const float* __restrict__ qkv,
                                                      unsigned short* __restrict__ ob) {
  int b = blockIdx.z, h = blockIdx.y, qt = blockIdx.x;
  int q0 = qt * 32;
  int tid = threadIdx.x;  // 256
  __shared__ float Qt[64][34];
  __shared__ float KV[64][68];
  __shared__ float Sc[32][200];
  const float* base = qkv + (size_t)b * T_ * (3 * D_);
  int ty = tid >> 4, tx = tid & 15;

#pragma unroll
  for (int i = 0; i < 2; ++i) {
    int item = tid + i * 256;
    int qi = item >> 4, dq = (item & 15) * 4;
    int row = q0 + qi;
    float4 qv = make_float4(0.f, 0.f, 0.f, 0.f);
    if (row < T_) qv = *(const float4*)(base + (size_t)row * (3 * D_) + h * HD_ + dq);
    Qt[dq + 0][qi] = qv.x;
    Qt[dq + 1][qi] = qv.y;
    Qt[dq + 2][qi] = qv.z;
    Qt[dq + 3][qi] = qv.w;
  }

  for (int kt = 0; kt < 4; ++kt) {
    int kb = kt * 64;
    __syncthreads();
#pragma unroll
    for (int i = 0; i < 4; ++i) {
      int item = tid + i * 256;
      int kk = item >> 4, dq = (item & 15) * 4;
      int krow = kb + kk;
      float4 kv = make_float4(0.f, 0.f, 0.f, 0.f);
      if (krow < T_) kv = *(const float4*)(base + (size_t)krow * (3 * D_) + D_ + h * HD_ + dq);
      KV[dq + 0][kk] = kv.x;
      KV[dq + 1][kk] = kv.y;
      KV[dq + 2][kk] = kv.z;
      KV[dq + 3][kk] = kv.w;
    }
    __syncthreads();
    float acc[2][4] = {};
#pragma unroll 16
    for (int d = 0; d < 64; ++d) {
      float a0 = Qt[d][ty * 2 + 0];
      float a1 = Qt[d][ty * 2 + 1];
      float4 bb = *(const float4*)&KV[d][tx * 4];
      acc[0][0] += a0 * bb.x; acc[0][1] += a0 * bb.y; acc[0][2] += a0 * bb.z; acc[0][3] += a0 * bb.w;
      acc[1][0] += a1 * bb.x; acc[1][1] += a1 * bb.y; acc[1][2] += a1 * bb.z; acc[1][3] += a1 * bb.w;
    }
#pragma unroll
    for (int r = 0; r < 2; ++r)
#pragma unroll
      for (int c = 0; c < 4; ++c) {
        int kc = kb + tx * 4 + c;
        if (kc < T_) Sc[ty * 2 + r][kc] = acc[r][c] * 0.125f;
      }
  }
  __syncthreads();

  {
    int r = tid >> 3, l8 = tid & 7;
    float mx = -1e30f;
    for (int k = l8; k < T_; k += 8) mx = fmaxf(mx, Sc[r][k]);
#pragma unroll
    for (int off = 4; off > 0; off >>= 1) mx = fmaxf(mx, __shfl_xor(mx, off, 8));
    float sum = 0.f;
    for (int k = l8; k < T_; k += 8) {
      float p = expf(Sc[r][k] - mx);
      Sc[r][k] = p;
      sum += p;
    }
#pragma unroll
    for (int off = 4; off > 0; off >>= 1) sum += __shfl_xor(sum, off, 8);
    float inv = 1.f / sum;
    for (int k = l8; k < T_; k += 8) Sc[r][k] *= inv;
  }

  float out[2][4] = {};
  for (int kt = 0; kt < 4; ++kt) {
    int kb = kt * 64;
    int kn = T_ - kb; if (kn > 64) kn = 64;
    __syncthreads();
#pragma unroll
    for (int i = 0; i < 4; ++i) {
      int item = tid + i * 256;
      int kk = item >> 4, dq = (item & 15) * 4;
      int krow = kb + kk;
      float4 vv = make_float4(0.f, 0.f, 0.f, 0.f);
      if (krow < T_) vv = *(const float4*)(base + (size_t)krow * (3 * D_) + 2 * D_ + h * HD_ + dq);
      *(float4*)&KV[kk][dq] = vv;
    }
    __syncthreads();
    for (int kk = 0; kk < kn; ++kk) {
      float p0 = Sc[ty * 2 + 0][kb + kk];
      float p1 = Sc[ty * 2 + 1][kb + kk];
      float4 vv = *(const float4*)&KV[kk][tx * 4];
      out[0][0] += p0 * vv.x; out[0][1] += p0 * vv.y; out[0][2] += p0 * vv.z; out[0][3] += p0 * vv.w;
      out[1][0] += p1 * vv.x; out[1][1] += p1 * vv.y; out[1][2] += p1 * vv.z; out[1][3] += p1 * vv.w;
    }
  }
#pragma unroll
  for (int r = 0; r < 2; ++r) {
    int row = q0 + ty * 2 + r;
    if (row < T_) {
      ushort4 ov;
      ov.x = f2bf(out[r][0]); ov.y = f2bf(out[r][1]);
      ov.z = f2bf(out[r][2]); ov.w = f2bf(out[r][3]);
      *(ushort4*)(ob + ((size_t)b * T_ + row) * D_ + h * HD_ + tx * 4) = ov;
    }
  }
}

// ---------------- final LN(row 0) + head ----------------
__global__ void head_kernel(const float* __restrict__ t, const float* __restrict__ nw,
                            const float* __restrict__ nb, const float* __restrict__ hw,
                            const float* __restrict__ hb, const int* __restrict__ idx,
                            float* __restrict__ out) {
  int b = blockIdx.x;
  int e = idx[b];
  int lane = threadIdx.x;  // 64
  const float* rp = t + (size_t)b * T_ * D_;
  float v[6];
  float s = 0.f;
#pragma unroll
  for (int j = 0; j < 6; ++j) { v[j] = rp[lane + j * 64]; s += v[j]; }
#pragma unroll
  for (int off = 1; off < 64; off <<= 1) s += __shfl_xor(s, off);
  float mean = s * (1.f / 384.f);
  float sq = 0.f;
#pragma unroll
  for (int j = 0; j < 6; ++j) { float dd = v[j] - mean; sq += dd * dd; }
#pragma unroll
  for (int off = 1; off < 64; off <<= 1) sq += __shfl_xor(sq, off);
  float rs = rsqrtf(sq * (1.f / 384.f) + 1e-6f);
  __shared__ float ln[D_];
#pragma unroll
  for (int j = 0; j < 6; ++j) {
    int d = lane + j * 64;
    ln[d] = (v[j] - mean) * rs * nw[e * D_ + d] + nb[e * D_ + d];
  }
  __syncthreads();
  if (lane < NC_) {
    float acc = hb[e * NC_ + lane];
    for (int d = 0; d < D_; ++d) acc += ln[d] * hw[((size_t)e * D_ + d) * NC_ + lane];
    out[b * NC_ + lane] = acc;
  }
}

extern "C" void kernel_launch(void* const* d_in, const int* in_sizes, int n_in,
                              void* d_out, int out_size, void* d_ws, size_t ws_size,
                              hipStream_t stream) {
  const float* x      = (const float*)d_in[0];
  const float* gate_w = (const float*)d_in[1];
  const float* gate_b = (const float*)d_in[2];
  const float* patch_w = (const float*)d_in[3];
  const float* patch_b = (const float*)d_in[4];
  const float* cls    = (const float*)d_in[5];
  const float* pos    = (const float*)d_in[6];
  const float* ln1_w  = (const float*)d_in[7];
  const float* ln1_b  = (const float*)d_in[8];
  const float* qkv_w  = (const float*)d_in[9];
  const float* qkv_b  = (const float*)d_in[10];
  const float* proj_w = (const float*)d_in[11];
  const float* proj_b = (const float*)d_in[12];
  const float* ln2_w  = (const float*)d_in[13];
  const float* ln2_b  = (const float*)d_in[14];
  const float* fc1_w  = (const float*)d_in[15];
  const float* fc1_b  = (const float*)d_in[16];
  const float* fc2_w  = (const float*)d_in[17];
  const float* fc2_b  = (const float*)d_in[18];
  const float* norm_w = (const float*)d_in[19];
  const float* norm_b = (const float*)d_in[20];
  const float* head_w = (const float*)d_in[21];
  const float* head_b = (const float*)d_in[22];

  float* ws = (float*)d_ws;
  int* idx   = (int*)ws;                              // 64 slots
  float* t   = ws + 64;                               // B*T*D f32
  float* qkv = t + (size_t)B_ * T_ * D_;              // B*T*3D f32
  unsigned short* hb = (unsigned short*)(qkv + (size_t)B_ * T_ * 3 * D_);  // B*T*D bf16
  unsigned short* ob = hb + (size_t)B_ * T_ * D_;     // B*T*D bf16
  unsigned short* ub = ob + (size_t)B_ * T_ * D_;     // B*T*FF bf16
  unsigned short* tq = ub + (size_t)B_ * T_ * FF_;    // E*3D*D bf16 (WT qkv)
  unsigned short* tp = tq + (size_t)E_ * D_ * 3 * D_; // E*D*D
  unsigned short* t1 = tp + (size_t)E_ * D_ * D_;     // E*FF*D
  unsigned short* t2 = t1 + (size_t)E_ * FF_ * D_;    // E*D*FF

  gate_kernel<<<B_, 256, 0, stream>>>(x, gate_w, gate_b, idx);
  cls_kernel<<<B_, D_, 0, stream>>>(cls, pos, idx, t);
  patch_kernel<<<dim3(14, B_), D_, 0, stream>>>(x, patch_w, patch_b, pos, idx, t);
  for (int l = 0; l < L_; ++l) {
    wtrans_kernel<<<dim3(1728, E_), 256, 0, stream>>>(qkv_w, proj_w, fc1_w, fc2_w,
                                                      tq, tp, t1, t2, l);
    ln_kernel<<<dim3(50, B_), 256, 0, stream>>>(t, hb, ln1_w, ln1_b, idx, l);
    gemm_mfma<0><<<dim3(18, 4, B_), 256, 0, stream>>>(hb, tq, qkv_b, qkv, idx, l, D_, 3 * D_);
    attn_kernel<<<dim3(7, H_, B_), 256, 0, stream>>>(qkv, ob);
    gemm_mfma<1><<<dim3(6, 4, B_), 256, 0, stream>>>(ob, tp, proj_b, t, idx, l, D_, D_);
    ln_kernel<<<dim3(50, B_), 256, 0, stream>>>(t, hb, ln2_w, ln2_b, idx, l);
    gemm_mfma<2><<<dim3(24, 4, B_), 256, 0, stream>>>(hb, t1, fc1_b, ub, idx, l, D_, FF_);
    gemm_mfma<1><<<dim3(6, 4, B_), 256, 0, stream>>>(ub, t2, fc2_b, t, idx, l, FF_, D_);
  }
  head_kernel<<<B_, 64, 0, stream>>>(t, norm_w, norm_b, head_w, head_b, idx, (float*)d_out);
}

// Round 4
// 1752.083 us; speedup vs baseline: 5.4738x; 4.4299x over previous
//
#include <hip/hip_runtime.h>
#include <math.h>

#define E_ 4
#define B_ 16
#define S_ 224
#define P_ 16
#define D_ 384
#define H_ 6
#define HD_ 64
#define L_ 12
#define FF_ 1536
#define NC_ 10
#define NP_ 196
#define T_ 197
#define GATE_K (3 * S_ * S_)  // 150528

typedef __attribute__((ext_vector_type(8))) short bf16x8;
typedef __attribute__((ext_vector_type(4))) float f32x4;

__device__ inline unsigned short f2bf(float f) {
  union { float f; unsigned u; } v; v.f = f;
  unsigned r = v.u + 0x7FFFu + ((v.u >> 16) & 1u);  // RNE
  return (unsigned short)(r >> 16);
}

// ---------------- gate ----------------
__global__ void gate_kernel(const float* __restrict__ x, const float* __restrict__ gw,
                            const float* __restrict__ gb, int* __restrict__ idx) {
  int b = blockIdx.x;
  int tid = threadIdx.x;
  const float* xb = x + (size_t)b * GATE_K;
  const float4* gw4 = (const float4*)gw;
  float4 acc = make_float4(0.f, 0.f, 0.f, 0.f);
  for (int i = tid; i < GATE_K; i += 256) {
    float xv = xb[i];
    float4 w = gw4[i];
    acc.x += xv * w.x; acc.y += xv * w.y; acc.z += xv * w.z; acc.w += xv * w.w;
  }
  __shared__ float4 red[256];
  red[tid] = acc;
  __syncthreads();
  for (int off = 128; off > 0; off >>= 1) {
    if (tid < off) {
      float4 o = red[tid + off];
      red[tid].x += o.x; red[tid].y += o.y; red[tid].z += o.z; red[tid].w += o.w;
    }
    __syncthreads();
  }
  if (tid == 0) {
    float v[4] = {red[0].x + gb[0], red[0].y + gb[1], red[0].z + gb[2], red[0].w + gb[3]};
    int best = 0;
    for (int e = 1; e < 4; ++e) if (v[e] > v[best]) best = e;
    idx[b] = best;
  }
}

// ---------------- cls row ----------------
__global__ void cls_kernel(const float* __restrict__ cls, const float* __restrict__ pos,
                           const int* __restrict__ idx, float* __restrict__ t) {
  int b = blockIdx.x;
  int d = threadIdx.x;
  int e = idx[b];
  t[((size_t)b * T_) * D_ + d] = cls[e * D_ + d] + pos[((size_t)e * T_) * D_ + d];
}

// ---------------- patch embed ----------------
__global__ void patch_kernel(const float* __restrict__ x, const float* __restrict__ pw,
                             const float* __restrict__ pb, const float* __restrict__ pos,
                             const int* __restrict__ idx, float* __restrict__ t) {
  int b = blockIdx.y;
  int e = idx[b];
  int m0 = blockIdx.x * 14;
  int tid = threadIdx.x;  // 384
  __shared__ float xin[14][768];
  for (int jj = tid; jj < 14 * 768; jj += 384) {
    int r = jj / 768, j = jj - r * 768;
    int m = m0 + r;
    int pr = m / 14, pc = m - pr * 14;
    int c = j >> 8, y = (j >> 4) & 15, xx = j & 15;
    xin[r][j] = x[(((size_t)b * 3 + c) * S_ + (pr * 16 + y)) * S_ + pc * 16 + xx];
  }
  __syncthreads();
  int d = tid;
  float acc[14];
#pragma unroll
  for (int r = 0; r < 14; ++r) acc[r] = 0.f;
  const float* pwe = pw + (size_t)e * 768 * D_;
  for (int k = 0; k < 768; ++k) {
    float wv = pwe[(size_t)k * D_ + d];
#pragma unroll
    for (int r = 0; r < 14; ++r) acc[r] += xin[r][k] * wv;
  }
  float bias = pb[e * D_ + d];
#pragma unroll
  for (int r = 0; r < 14; ++r) {
    int row = 1 + m0 + r;
    t[((size_t)b * T_ + row) * D_ + d] = acc[r] + bias + pos[((size_t)e * T_ + row) * D_ + d];
  }
}

// ---------------- layernorm -> bf16 out ----------------
__global__ void ln_kernel(const float* __restrict__ in, unsigned short* __restrict__ out,
                          const float* __restrict__ w, const float* __restrict__ bc,
                          const int* __restrict__ idx, int l) {
  int b = blockIdx.y;
  int row = blockIdx.x * 4 + (threadIdx.x >> 6);
  if (row >= T_) return;
  int lane = threadIdx.x & 63;
  int e = idx[b];
  const float* rp = in + ((size_t)b * T_ + row) * D_;
  float v[6];
  float s = 0.f;
#pragma unroll
  for (int j = 0; j < 6; ++j) { v[j] = rp[lane + j * 64]; s += v[j]; }
#pragma unroll
  for (int off = 1; off < 64; off <<= 1) s += __shfl_xor(s, off);
  float mean = s * (1.f / 384.f);
  float sq = 0.f;
#pragma unroll
  for (int j = 0; j < 6; ++j) { float dd = v[j] - mean; sq += dd * dd; }
#pragma unroll
  for (int off = 1; off < 64; off <<= 1) sq += __shfl_xor(sq, off);
  float rs = rsqrtf(sq * (1.f / 384.f) + 1e-6f);
  const float* wrow = w + ((size_t)e * L_ + l) * D_;
  const float* brow = bc + ((size_t)e * L_ + l) * D_;
  unsigned short* op = out + ((size_t)b * T_ + row) * D_;
#pragma unroll
  for (int j = 0; j < 6; ++j) {
    int d = lane + j * 64;
    op[d] = f2bf((v[j] - mean) * rs * wrow[d] + brow[d]);
  }
}

// ---------------- weight transpose: W[K][N] fp32 -> WT[slot][e][N][K] bf16 ----------------
// blockIdx.z = slot (dst layer slot; src layer = lsrc_base + slot)
__global__ __launch_bounds__(256) void wtrans_kernel(
    const float* __restrict__ qw, const float* __restrict__ pw,
    const float* __restrict__ f1, const float* __restrict__ f2,
    unsigned short* __restrict__ tq, unsigned short* __restrict__ tp,
    unsigned short* __restrict__ t1, unsigned short* __restrict__ t2, int lsrc_base) {
  int e = blockIdx.y;
  int slot = blockIdx.z;
  int l = lsrc_base + slot;
  int r = blockIdx.x;  // 0..1727
  const float* src; unsigned short* dst; int K, N, kt, nt;
  if (r < 432) {        // qkv: 384x1152, 12x36 tiles
    K = 384; N = 1152;
    src = qw + (size_t)(e * L_ + l) * K * N; dst = tq + (size_t)(slot * E_ + e) * K * N;
    kt = r / 36; nt = r % 36;
  } else if (r < 576) { // proj: 384x384, 12x12
    r -= 432; K = 384; N = 384;
    src = pw + (size_t)(e * L_ + l) * K * N; dst = tp + (size_t)(slot * E_ + e) * K * N;
    kt = r / 12; nt = r % 12;
  } else if (r < 1152) {// fc1: 384x1536, 12x48
    r -= 576; K = 384; N = 1536;
    src = f1 + (size_t)(e * L_ + l) * K * N; dst = t1 + (size_t)(slot * E_ + e) * K * N;
    kt = r / 48; nt = r % 48;
  } else {              // fc2: 1536x384, 48x12
    r -= 1152; K = 1536; N = 384;
    src = f2 + (size_t)(e * L_ + l) * K * N; dst = t2 + (size_t)(slot * E_ + e) * K * N;
    kt = r / 12; nt = r % 12;
  }
  int k0 = kt * 32, n0 = nt * 32;
  __shared__ float tile[32][33];
  int t = threadIdx.x;
  int rr = t >> 3, c4 = (t & 7) * 4;
  float4 v = *(const float4*)(src + (size_t)(k0 + rr) * N + n0 + c4);
  tile[rr][c4 + 0] = v.x; tile[rr][c4 + 1] = v.y;
  tile[rr][c4 + 2] = v.z; tile[rr][c4 + 3] = v.w;
  __syncthreads();
  int n = t >> 3, k4 = (t & 7) * 4;
  ushort4 o;
  o.x = f2bf(tile[k4 + 0][n]); o.y = f2bf(tile[k4 + 1][n]);
  o.z = f2bf(tile[k4 + 2][n]); o.w = f2bf(tile[k4 + 3][n]);
  *(ushort4*)(dst + (size_t)(n0 + n) * K + k0 + k4) = o;
}

// ---------------- MFMA bf16 GEMM: Out[b] = A[b](bf16) @ WT[e]^T + bias ----------------
// EPI: 0 = store fp32, 1 = fp32 residual add, 2 = GELU -> bf16, 3 = plain bf16 store.
template <int EPI>
__global__ __launch_bounds__(256, 4) void gemm_mfma(
    const unsigned short* __restrict__ A, const unsigned short* __restrict__ WT,
    const float* __restrict__ bias, void* __restrict__ Out,
    const int* __restrict__ idx, int l, int K, int N) {
  int b = blockIdx.z;
  int e = idx[b];
  int n0 = blockIdx.x * 64, m0 = blockIdx.y * 64;
  int tid = threadIdx.x;
  const unsigned short* Ab = A + (size_t)b * T_ * K;
  const unsigned short* Wb = WT + (size_t)e * N * K;
  __shared__ unsigned short Asl[4][64][8];
  __shared__ unsigned short Bsl[4][64][8];
  f32x4 acc[2][2];
#pragma unroll
  for (int i = 0; i < 2; ++i)
#pragma unroll
    for (int j = 0; j < 2; ++j) acc[i][j] = (f32x4){0.f, 0.f, 0.f, 0.f};
  int wid = tid >> 6, lane = tid & 63;
  int wm = (wid >> 1) * 32, wn = (wid & 1) * 32;
  int lrow = lane & 15, lk = lane >> 4;
  int ar = tid >> 2, akq = tid & 3;
  for (int k0 = 0; k0 < K; k0 += 32) {
    uint4 av = make_uint4(0, 0, 0, 0);
    if (m0 + ar < T_) av = *(const uint4*)(Ab + (size_t)(m0 + ar) * K + k0 + akq * 8);
    uint4 bv = *(const uint4*)(Wb + (size_t)(n0 + ar) * K + k0 + akq * 8);
    __syncthreads();
    *(uint4*)&Asl[akq][ar][0] = av;
    *(uint4*)&Bsl[akq][ar][0] = bv;
    __syncthreads();
    bf16x8 a0 = *(const bf16x8*)&Asl[lk][wm + lrow][0];
    bf16x8 a1 = *(const bf16x8*)&Asl[lk][wm + 16 + lrow][0];
    bf16x8 b0 = *(const bf16x8*)&Bsl[lk][wn + lrow][0];
    bf16x8 b1 = *(const bf16x8*)&Bsl[lk][wn + 16 + lrow][0];
    acc[0][0] = __builtin_amdgcn_mfma_f32_16x16x32_bf16(a0, b0, acc[0][0], 0, 0, 0);
    acc[0][1] = __builtin_amdgcn_mfma_f32_16x16x32_bf16(a0, b1, acc[0][1], 0, 0, 0);
    acc[1][0] = __builtin_amdgcn_mfma_f32_16x16x32_bf16(a1, b0, acc[1][0], 0, 0, 0);
    acc[1][1] = __builtin_amdgcn_mfma_f32_16x16x32_bf16(a1, b1, acc[1][1], 0, 0, 0);
  }
  const float* brow = bias + ((size_t)e * L_ + l) * N + n0;
#pragma unroll
  for (int fm = 0; fm < 2; ++fm)
#pragma unroll
    for (int fn = 0; fn < 2; ++fn) {
      int col = wn + fn * 16 + lrow;
      float bval = brow[col];
#pragma unroll
      for (int r = 0; r < 4; ++r) {
        int row = m0 + wm + fm * 16 + lk * 4 + r;
        if (row >= T_) continue;
        float val = acc[fm][fn][r] + bval;
        if (EPI == 0) {
          ((float*)Out)[((size_t)b * T_ + row) * N + n0 + col] = val;
        } else if (EPI == 1) {
          float* p = (float*)Out + ((size_t)b * T_ + row) * N + n0 + col;
          *p = *p + val;
        } else if (EPI == 2) {
          val = 0.5f * val * (1.f + erff(val * 0.70710678118654752f));
          ((unsigned short*)Out)[((size_t)b * T_ + row) * N + n0 + col] = f2bf(val);
        } else {
          ((unsigned short*)Out)[((size_t)b * T_ + row) * N + n0 + col] = f2bf(val);
        }
      }
    }
}

// ---------------- attention v3: MFMA bf16, 2 waves/block ----------------
// Block (qt, h, b): 128 threads, wave w handles q-rows qt*32 + w*16 .. +15.
// QK^T: A/B frags direct from global bf16 qkv. Softmax in-register (C-layout).
// P -> LDS bf16; V^T staged in LDS once; PV via MFMA.
__global__ __launch_bounds__(128, 2) void attn_mfma(const unsigned short* __restrict__ qkvb,
                                                    unsigned short* __restrict__ ob) {
  int b = blockIdx.z, h = blockIdx.y, qt = blockIdx.x;
  int tid = threadIdx.x;  // 128
  int w = tid >> 6, lane = tid & 63;
  int q0 = qt * 32 + w * 16;
  __shared__ unsigned short Vt[64][232];      // V^T[d][kv], stride 232 (464B, 16B-aligned)
  __shared__ unsigned short Pl[2][16][232];   // per-wave P[q][kv]
  const unsigned short* base = qkvb + (size_t)b * T_ * (3 * D_) + h * HD_;

  // ---- stage V^T (all 128 threads; coalesced 128B row reads) ----
  {
    int d2 = (tid & 31) * 2;
    int kvh = tid >> 5;  // 0..3
    const unsigned short* vb = base + 2 * D_;
    for (int i = 0; i < 56; ++i) {
      int kv = kvh * 56 + i;
      int kvc = kv < T_ ? kv : T_ - 1;
      unsigned int vv = *(const unsigned int*)(vb + (size_t)kvc * (3 * D_) + d2);
      Vt[d2][kv] = (unsigned short)(vv & 0xffffu);
      Vt[d2 + 1][kv] = (unsigned short)(vv >> 16);
    }
  }

  int c16 = lane & 15, g4 = lane >> 4;

  // ---- Q A-frags (row = lane&15, k = g4*8 + ks*32) ----
  int qrow = q0 + c16; if (qrow > T_ - 1) qrow = T_ - 1;
  bf16x8 aq[2];
#pragma unroll
  for (int ks = 0; ks < 2; ++ks)
    aq[ks] = *(const bf16x8*)(base + (size_t)qrow * (3 * D_) + ks * 32 + g4 * 8);

  // ---- QK^T: sc[nf] covers kv cols nf*16..+15 ----
  f32x4 sc[14];
#pragma unroll
  for (int nf = 0; nf < 14; ++nf) sc[nf] = (f32x4){0.f, 0.f, 0.f, 0.f};
  const unsigned short* kb = base + D_;
#pragma unroll
  for (int nf = 0; nf < 14; ++nf) {
    int krow = nf * 16 + c16; if (krow > T_ - 1) krow = T_ - 1;
#pragma unroll
    for (int ks = 0; ks < 2; ++ks) {
      bf16x8 bk = *(const bf16x8*)(kb + (size_t)krow * (3 * D_) + ks * 32 + g4 * 8);
      sc[nf] = __builtin_amdgcn_mfma_f32_16x16x32_bf16(aq[ks], bk, sc[nf], 0, 0, 0);
    }
  }

  // ---- softmax (per lane: 4 q-rows x 14 cols; reduce across 16-lane groups) ----
  float mx[4], sm[4];
#pragma unroll
  for (int r = 0; r < 4; ++r) mx[r] = -1e30f;
#pragma unroll
  for (int nf = 0; nf < 14; ++nf) {
    bool valid = (nf * 16 + c16) < T_;
#pragma unroll
    for (int r = 0; r < 4; ++r) {
      float s = valid ? sc[nf][r] * 0.125f : -1e30f;
      sc[nf][r] = s;
      mx[r] = fmaxf(mx[r], s);
    }
  }
#pragma unroll
  for (int r = 0; r < 4; ++r) {
#pragma unroll
    for (int off = 1; off < 16; off <<= 1) mx[r] = fmaxf(mx[r], __shfl_xor(mx[r], off, 16));
    sm[r] = 0.f;
  }
#pragma unroll
  for (int nf = 0; nf < 14; ++nf)
#pragma unroll
    for (int r = 0; r < 4; ++r) {
      float p = __expf(sc[nf][r] - mx[r]);  // masked cols -> 0
      sc[nf][r] = p;
      sm[r] += p;
    }
#pragma unroll
  for (int r = 0; r < 4; ++r) {
#pragma unroll
    for (int off = 1; off < 16; off <<= 1) sm[r] += __shfl_xor(sm[r], off, 16);
    sm[r] = 1.f / sm[r];
  }
#pragma unroll
  for (int nf = 0; nf < 14; ++nf) {
    int col = nf * 16 + c16;
#pragma unroll
    for (int r = 0; r < 4; ++r)
      Pl[w][g4 * 4 + r][col] = f2bf(sc[nf][r] * sm[r]);
  }
  __syncthreads();  // Vt + Pl visible

  // ---- PV: O[16][64] += P[16][224] @ V[224][64] ----
  f32x4 oacc[4];
#pragma unroll
  for (int nf = 0; nf < 4; ++nf) oacc[nf] = (f32x4){0.f, 0.f, 0.f, 0.f};
#pragma unroll
  for (int ks = 0; ks < 7; ++ks) {
    bf16x8 ap = *(const bf16x8*)&Pl[w][c16][ks * 32 + g4 * 8];
#pragma unroll
    for (int nf = 0; nf < 4; ++nf) {
      bf16x8 bv = *(const bf16x8*)&Vt[nf * 16 + c16][ks * 32 + g4 * 8];
      oacc[nf] = __builtin_amdgcn_mfma_f32_16x16x32_bf16(ap, bv, oacc[nf], 0, 0, 0);
    }
  }

  // ---- store O bf16 (C-layout: col=d, row=q) ----
#pragma unroll
  for (int nf = 0; nf < 4; ++nf) {
    int d = nf * 16 + c16;
#pragma unroll
    for (int r = 0; r < 4; ++r) {
      int q = q0 + g4 * 4 + r;
      if (q < T_)
        ob[((size_t)b * T_ + q) * D_ + h * HD_ + d] = f2bf(oacc[nf][r]);
    }
  }
}

// ---------------- final LN(row 0) + head ----------------
__global__ void head_kernel(const float* __restrict__ t, const float* __restrict__ nw,
                            const float* __restrict__ nb, const float* __restrict__ hw,
                            const float* __restrict__ hb, const int* __restrict__ idx,
                            float* __restrict__ out) {
  int b = blockIdx.x;
  int e = idx[b];
  int lane = threadIdx.x;  // 64
  const float* rp = t + (size_t)b * T_ * D_;
  float v[6];
  float s = 0.f;
#pragma unroll
  for (int j = 0; j < 6; ++j) { v[j] = rp[lane + j * 64]; s += v[j]; }
#pragma unroll
  for (int off = 1; off < 64; off <<= 1) s += __shfl_xor(s, off);
  float mean = s * (1.f / 384.f);
  float sq = 0.f;
#pragma unroll
  for (int j = 0; j < 6; ++j) { float dd = v[j] - mean; sq += dd * dd; }
#pragma unroll
  for (int off = 1; off < 64; off <<= 1) sq += __shfl_xor(sq, off);
  float rs = rsqrtf(sq * (1.f / 384.f) + 1e-6f);
  __shared__ float ln[D_];
#pragma unroll
  for (int j = 0; j < 6; ++j) {
    int d = lane + j * 64;
    ln[d] = (v[j] - mean) * rs * nw[e * D_ + d] + nb[e * D_ + d];
  }
  __syncthreads();
  if (lane < NC_) {
    float acc = hb[e * NC_ + lane];
    for (int d = 0; d < D_; ++d) acc += ln[d] * hw[((size_t)e * D_ + d) * NC_ + lane];
    out[b * NC_ + lane] = acc;
  }
}

extern "C" void kernel_launch(void* const* d_in, const int* in_sizes, int n_in,
                              void* d_out, int out_size, void* d_ws, size_t ws_size,
                              hipStream_t stream) {
  const float* x      = (const float*)d_in[0];
  const float* gate_w = (const float*)d_in[1];
  const float* gate_b = (const float*)d_in[2];
  const float* patch_w = (const float*)d_in[3];
  const float* patch_b = (const float*)d_in[4];
  const float* cls    = (const float*)d_in[5];
  const float* pos    = (const float*)d_in[6];
  const float* ln1_w  = (const float*)d_in[7];
  const float* ln1_b  = (const float*)d_in[8];
  const float* qkv_w  = (const float*)d_in[9];
  const float* qkv_b  = (const float*)d_in[10];
  const float* proj_w = (const float*)d_in[11];
  const float* proj_b = (const float*)d_in[12];
  const float* ln2_w  = (const float*)d_in[13];
  const float* ln2_b  = (const float*)d_in[14];
  const float* fc1_w  = (const float*)d_in[15];
  const float* fc1_b  = (const float*)d_in[16];
  const float* fc2_w  = (const float*)d_in[17];
  const float* fc2_b  = (const float*)d_in[18];
  const float* norm_w = (const float*)d_in[19];
  const float* norm_b = (const float*)d_in[20];
  const float* head_w = (const float*)d_in[21];
  const float* head_b = (const float*)d_in[22];

  const size_t SQ = (size_t)D_ * 3 * D_, SP = (size_t)D_ * D_;
  const size_t S1 = (size_t)D_ * FF_, S2 = (size_t)FF_ * D_;
  const size_t WSET = SQ + SP + S1 + S2;  // bf16 elements per (layer, expert)

  float* ws = (float*)d_ws;
  int* idx = (int*)ws;                                  // 64 slots
  float* t = ws + 64;                                   // B*T*D f32
  unsigned short* qkvb = (unsigned short*)(t + (size_t)B_ * T_ * D_);  // B*T*3D bf16
  unsigned short* hb = qkvb + (size_t)B_ * T_ * 3 * D_; // B*T*D bf16
  unsigned short* ob = hb + (size_t)B_ * T_ * D_;       // B*T*D bf16
  unsigned short* ub = ob + (size_t)B_ * T_ * D_;       // B*T*FF bf16
  unsigned short* wbase = ub + (size_t)B_ * T_ * FF_;
  size_t fixed_bytes = (size_t)((char*)wbase - (char*)d_ws);
  bool hoist = ws_size >= fixed_bytes + WSET * 2ull * E_ * L_ + 4096;
  int NL = hoist ? L_ : 1;
  unsigned short* tq = wbase;
  unsigned short* tp = tq + (size_t)NL * E_ * SQ;
  unsigned short* t1 = tp + (size_t)NL * E_ * SP;
  unsigned short* t2 = t1 + (size_t)NL * E_ * S1;

  gate_kernel<<<B_, 256, 0, stream>>>(x, gate_w, gate_b, idx);
  cls_kernel<<<B_, D_, 0, stream>>>(cls, pos, idx, t);
  patch_kernel<<<dim3(14, B_), D_, 0, stream>>>(x, patch_w, patch_b, pos, idx, t);
  if (hoist)
    wtrans_kernel<<<dim3(1728, E_, L_), 256, 0, stream>>>(qkv_w, proj_w, fc1_w, fc2_w,
                                                          tq, tp, t1, t2, 0);
  for (int l = 0; l < L_; ++l) {
    int slot = hoist ? l : 0;
    if (!hoist)
      wtrans_kernel<<<dim3(1728, E_, 1), 256, 0, stream>>>(qkv_w, proj_w, fc1_w, fc2_w,
                                                           tq, tp, t1, t2, l);
    unsigned short* tql = tq + (size_t)slot * E_ * SQ;
    unsigned short* tpl = tp + (size_t)slot * E_ * SP;
    unsigned short* t1l = t1 + (size_t)slot * E_ * S1;
    unsigned short* t2l = t2 + (size_t)slot * E_ * S2;
    ln_kernel<<<dim3(50, B_), 256, 0, stream>>>(t, hb, ln1_w, ln1_b, idx, l);
    gemm_mfma<3><<<dim3(18, 4, B_), 256, 0, stream>>>(hb, tql, qkv_b, qkvb, idx, l, D_, 3 * D_);
    attn_mfma<<<dim3(7, H_, B_), 128, 0, stream>>>(qkvb, ob);
    gemm_mfma<1><<<dim3(6, 4, B_), 256, 0, stream>>>(ob, tpl, proj_b, t, idx, l, D_, D_);
    ln_kernel<<<dim3(50, B_), 256, 0, stream>>>(t, hb, ln2_w, ln2_b, idx, l);
    gemm_mfma<2><<<dim3(24, 4, B_), 256, 0, stream>>>(hb, t1l, fc1_b, ub, idx, l, D_, FF_);
    gemm_mfma<1><<<dim3(6, 4, B_), 256, 0, stream>>>(ub, t2l, fc2_b, t, idx, l, FF_, D_);
  }
  head_kernel<<<B_, 64, 0, stream>>>(t, norm_w, norm_b, head_w, head_b, idx, (float*)d_out);
}

// Round 5
// 1692.480 us; speedup vs baseline: 5.6665x; 1.0352x over previous
//
#include <hip/hip_runtime.h>
#include <math.h>

#define E_ 4
#define B_ 16
#define S_ 224
#define P_ 16
#define D_ 384
#define H_ 6
#define HD_ 64
#define L_ 12
#define FF_ 1536
#define NC_ 10
#define NP_ 196
#define T_ 197
#define GATE_K (3 * S_ * S_)  // 150528
#define GSPLIT 32
#define GCHUNK (GATE_K / GSPLIT)  // 4704

typedef __attribute__((ext_vector_type(8))) short bf16x8;
typedef __attribute__((ext_vector_type(4))) float f32x4;

__device__ inline unsigned short f2bf(float f) {
  union { float f; unsigned u; } v; v.f = f;
  unsigned r = v.u + 0x7FFFu + ((v.u >> 16) & 1u);  // RNE
  return (unsigned short)(r >> 16);
}

// ---------------- gate phase 1: partial dot products ----------------
__global__ __launch_bounds__(256) void gate_partial(const float* __restrict__ x,
                                                    const float* __restrict__ gw,
                                                    float4* __restrict__ part) {
  int b = blockIdx.x, s = blockIdx.y, tid = threadIdx.x;
  const float* xb = x + (size_t)b * GATE_K;
  const float4* gw4 = (const float4*)gw;
  int i0 = s * GCHUNK, i1 = i0 + GCHUNK;
  float4 acc = make_float4(0.f, 0.f, 0.f, 0.f);
  for (int i = i0 + tid; i < i1; i += 256) {
    float xv = xb[i];
    float4 w = gw4[i];
    acc.x += xv * w.x; acc.y += xv * w.y; acc.z += xv * w.z; acc.w += xv * w.w;
  }
  __shared__ float4 red[256];
  red[tid] = acc;
  __syncthreads();
  for (int off = 128; off > 0; off >>= 1) {
    if (tid < off) {
      float4 o = red[tid + off];
      red[tid].x += o.x; red[tid].y += o.y; red[tid].z += o.z; red[tid].w += o.w;
    }
    __syncthreads();
  }
  if (tid == 0) part[b * GSPLIT + s] = red[0];
}

// ---------------- gate phase 2: reduce + argmax ----------------
__global__ void gate_reduce(const float4* __restrict__ part, const float* __restrict__ gb,
                            int* __restrict__ idx) {
  int b = blockIdx.x;
  int lane = threadIdx.x;  // 64
  float4 a = make_float4(0.f, 0.f, 0.f, 0.f);
  if (lane < GSPLIT) a = part[b * GSPLIT + lane];
#pragma unroll
  for (int off = 1; off < 64; off <<= 1) {
    a.x += __shfl_xor(a.x, off);
    a.y += __shfl_xor(a.y, off);
    a.z += __shfl_xor(a.z, off);
    a.w += __shfl_xor(a.w, off);
  }
  if (lane == 0) {
    float v[4] = {a.x + gb[0], a.y + gb[1], a.z + gb[2], a.w + gb[3]};
    int best = 0;
    for (int e = 1; e < 4; ++e) if (v[e] > v[best]) best = e;
    idx[b] = best;
  }
}

// ---------------- cls row ----------------
__global__ void cls_kernel(const float* __restrict__ cls, const float* __restrict__ pos,
                           const int* __restrict__ idx, float* __restrict__ t) {
  int b = blockIdx.x;
  int d = threadIdx.x;
  int e = idx[b];
  t[((size_t)b * T_) * D_ + d] = cls[e * D_ + d] + pos[((size_t)e * T_) * D_ + d];
}

// ---------------- patch embed ----------------
__global__ void patch_kernel(const float* __restrict__ x, const float* __restrict__ pw,
                             const float* __restrict__ pb, const float* __restrict__ pos,
                             const int* __restrict__ idx, float* __restrict__ t) {
  int b = blockIdx.y;
  int e = idx[b];
  int m0 = blockIdx.x * 14;
  int tid = threadIdx.x;  // 384
  __shared__ float xin[14][768];
  for (int jj = tid; jj < 14 * 768; jj += 384) {
    int r = jj / 768, j = jj - r * 768;
    int m = m0 + r;
    int pr = m / 14, pc = m - pr * 14;
    int c = j >> 8, y = (j >> 4) & 15, xx = j & 15;
    xin[r][j] = x[(((size_t)b * 3 + c) * S_ + (pr * 16 + y)) * S_ + pc * 16 + xx];
  }
  __syncthreads();
  int d = tid;
  float acc[14];
#pragma unroll
  for (int r = 0; r < 14; ++r) acc[r] = 0.f;
  const float* pwe = pw + (size_t)e * 768 * D_;
  for (int k = 0; k < 768; ++k) {
    float wv = pwe[(size_t)k * D_ + d];
#pragma unroll
    for (int r = 0; r < 14; ++r) acc[r] += xin[r][k] * wv;
  }
  float bias = pb[e * D_ + d];
#pragma unroll
  for (int r = 0; r < 14; ++r) {
    int row = 1 + m0 + r;
    t[((size_t)b * T_ + row) * D_ + d] = acc[r] + bias + pos[((size_t)e * T_ + row) * D_ + d];
  }
}

// ---------------- layernorm -> bf16 out ----------------
__global__ void ln_kernel(const float* __restrict__ in, unsigned short* __restrict__ out,
                          const float* __restrict__ w, const float* __restrict__ bc,
                          const int* __restrict__ idx, int l) {
  int b = blockIdx.y;
  int row = blockIdx.x * 4 + (threadIdx.x >> 6);
  if (row >= T_) return;
  int lane = threadIdx.x & 63;
  int e = idx[b];
  const float* rp = in + ((size_t)b * T_ + row) * D_;
  float v[6];
  float s = 0.f;
#pragma unroll
  for (int j = 0; j < 6; ++j) { v[j] = rp[lane + j * 64]; s += v[j]; }
#pragma unroll
  for (int off = 1; off < 64; off <<= 1) s += __shfl_xor(s, off);
  float mean = s * (1.f / 384.f);
  float sq = 0.f;
#pragma unroll
  for (int j = 0; j < 6; ++j) { float dd = v[j] - mean; sq += dd * dd; }
#pragma unroll
  for (int off = 1; off < 64; off <<= 1) sq += __shfl_xor(sq, off);
  float rs = rsqrtf(sq * (1.f / 384.f) + 1e-6f);
  const float* wrow = w + ((size_t)e * L_ + l) * D_;
  const float* brow = bc + ((size_t)e * L_ + l) * D_;
  unsigned short* op = out + ((size_t)b * T_ + row) * D_;
#pragma unroll
  for (int j = 0; j < 6; ++j) {
    int d = lane + j * 64;
    op[d] = f2bf((v[j] - mean) * rs * wrow[d] + brow[d]);
  }
}

// ---------------- weight transpose: W[K][N] fp32 -> WT[slot][e][N][K] bf16 ----------------
__global__ __launch_bounds__(256) void wtrans_kernel(
    const float* __restrict__ qw, const float* __restrict__ pw,
    const float* __restrict__ f1, const float* __restrict__ f2,
    unsigned short* __restrict__ tq, unsigned short* __restrict__ tp,
    unsigned short* __restrict__ t1, unsigned short* __restrict__ t2, int lsrc_base) {
  int e = blockIdx.y;
  int slot = blockIdx.z;
  int l = lsrc_base + slot;
  int r = blockIdx.x;  // 0..1727
  const float* src; unsigned short* dst; int K, N, kt, nt;
  if (r < 432) {        // qkv: 384x1152
    K = 384; N = 1152;
    src = qw + (size_t)(e * L_ + l) * K * N; dst = tq + (size_t)(slot * E_ + e) * K * N;
    kt = r / 36; nt = r % 36;
  } else if (r < 576) { // proj: 384x384
    r -= 432; K = 384; N = 384;
    src = pw + (size_t)(e * L_ + l) * K * N; dst = tp + (size_t)(slot * E_ + e) * K * N;
    kt = r / 12; nt = r % 12;
  } else if (r < 1152) {// fc1: 384x1536
    r -= 576; K = 384; N = 1536;
    src = f1 + (size_t)(e * L_ + l) * K * N; dst = t1 + (size_t)(slot * E_ + e) * K * N;
    kt = r / 48; nt = r % 48;
  } else {              // fc2: 1536x384
    r -= 1152; K = 1536; N = 384;
    src = f2 + (size_t)(e * L_ + l) * K * N; dst = t2 + (size_t)(slot * E_ + e) * K * N;
    kt = r / 12; nt = r % 12;
  }
  int k0 = kt * 32, n0 = nt * 32;
  __shared__ float tile[32][33];
  int t = threadIdx.x;
  int rr = t >> 3, c4 = (t & 7) * 4;
  float4 v = *(const float4*)(src + (size_t)(k0 + rr) * N + n0 + c4);
  tile[rr][c4 + 0] = v.x; tile[rr][c4 + 1] = v.y;
  tile[rr][c4 + 2] = v.z; tile[rr][c4 + 3] = v.w;
  __syncthreads();
  int n = t >> 3, k4 = (t & 7) * 4;
  ushort4 o;
  o.x = f2bf(tile[k4 + 0][n]); o.y = f2bf(tile[k4 + 1][n]);
  o.z = f2bf(tile[k4 + 2][n]); o.w = f2bf(tile[k4 + 3][n]);
  *(ushort4*)(dst + (size_t)(n0 + n) * K + k0 + k4) = o;
}

// ---------------- MFMA bf16 GEMM, 64x128 tile ----------------
// 4 waves as 2x2: wave covers 32 rows x 64 cols (2x4 16x16 frags). BK=32.
// EPI: 0 = store fp32, 1 = fp32 residual add, 2 = GELU -> bf16, 3 = plain bf16 store.
template <int EPI>
__global__ __launch_bounds__(256, 4) void gemm_mfma(
    const unsigned short* __restrict__ A, const unsigned short* __restrict__ WT,
    const float* __restrict__ bias, void* __restrict__ Out,
    const int* __restrict__ idx, int l, int K, int N) {
  int b = blockIdx.z;
  int e = idx[b];
  int n0 = blockIdx.x * 128, m0 = blockIdx.y * 64;
  int tid = threadIdx.x;
  const unsigned short* Ab = A + (size_t)b * T_ * K;
  const unsigned short* Wb = WT + (size_t)e * N * K;
  __shared__ unsigned short Asl[4][64][8];   // [kgrp][row][j]
  __shared__ unsigned short Bsl[4][128][8];  // [kgrp][col][j]
  f32x4 acc[2][4];
#pragma unroll
  for (int i = 0; i < 2; ++i)
#pragma unroll
    for (int j = 0; j < 4; ++j) acc[i][j] = (f32x4){0.f, 0.f, 0.f, 0.f};
  int wid = tid >> 6, lane = tid & 63;
  int wm = (wid >> 1) * 32, wn = (wid & 1) * 64;
  int lrow = lane & 15, lk = lane >> 4;
  int ar = tid >> 2, akq = tid & 3;
  for (int k0 = 0; k0 < K; k0 += 32) {
    uint4 av = make_uint4(0, 0, 0, 0);
    if (m0 + ar < T_) av = *(const uint4*)(Ab + (size_t)(m0 + ar) * K + k0 + akq * 8);
    uint4 bv0 = *(const uint4*)(Wb + (size_t)(n0 + ar) * K + k0 + akq * 8);
    uint4 bv1 = *(const uint4*)(Wb + (size_t)(n0 + 64 + ar) * K + k0 + akq * 8);
    __syncthreads();
    *(uint4*)&Asl[akq][ar][0] = av;
    *(uint4*)&Bsl[akq][ar][0] = bv0;
    *(uint4*)&Bsl[akq][64 + ar][0] = bv1;
    __syncthreads();
    bf16x8 a0 = *(const bf16x8*)&Asl[lk][wm + lrow][0];
    bf16x8 a1 = *(const bf16x8*)&Asl[lk][wm + 16 + lrow][0];
#pragma unroll
    for (int fn = 0; fn < 4; ++fn) {
      bf16x8 bb = *(const bf16x8*)&Bsl[lk][wn + fn * 16 + lrow][0];
      acc[0][fn] = __builtin_amdgcn_mfma_f32_16x16x32_bf16(a0, bb, acc[0][fn], 0, 0, 0);
      acc[1][fn] = __builtin_amdgcn_mfma_f32_16x16x32_bf16(a1, bb, acc[1][fn], 0, 0, 0);
    }
  }
  const float* brow = bias + ((size_t)e * L_ + l) * N + n0;
#pragma unroll
  for (int fm = 0; fm < 2; ++fm)
#pragma unroll
    for (int fn = 0; fn < 4; ++fn) {
      int col = wn + fn * 16 + lrow;
      float bval = brow[col];
#pragma unroll
      for (int r = 0; r < 4; ++r) {
        int row = m0 + wm + fm * 16 + lk * 4 + r;
        if (row >= T_) continue;
        float val = acc[fm][fn][r] + bval;
        if (EPI == 0) {
          ((float*)Out)[((size_t)b * T_ + row) * N + n0 + col] = val;
        } else if (EPI == 1) {
          float* p = (float*)Out + ((size_t)b * T_ + row) * N + n0 + col;
          *p = *p + val;
        } else if (EPI == 2) {
          val = 0.5f * val * (1.f + erff(val * 0.70710678118654752f));
          ((unsigned short*)Out)[((size_t)b * T_ + row) * N + n0 + col] = f2bf(val);
        } else {
          ((unsigned short*)Out)[((size_t)b * T_ + row) * N + n0 + col] = f2bf(val);
        }
      }
    }
}

// ---------------- attention: MFMA bf16, 2 waves/block ----------------
__global__ __launch_bounds__(128, 2) void attn_mfma(const unsigned short* __restrict__ qkvb,
                                                    unsigned short* __restrict__ ob) {
  int b = blockIdx.z, h = blockIdx.y, qt = blockIdx.x;
  int tid = threadIdx.x;  // 128
  int w = tid >> 6, lane = tid & 63;
  int q0 = qt * 32 + w * 16;
  __shared__ unsigned short Vt[64][232];
  __shared__ unsigned short Pl[2][16][232];
  const unsigned short* base = qkvb + (size_t)b * T_ * (3 * D_) + h * HD_;

  {
    int d2 = (tid & 31) * 2;
    int kvh = tid >> 5;  // 0..3
    const unsigned short* vb = base + 2 * D_;
    for (int i = 0; i < 56; ++i) {
      int kv = kvh * 56 + i;
      int kvc = kv < T_ ? kv : T_ - 1;
      unsigned int vv = *(const unsigned int*)(vb + (size_t)kvc * (3 * D_) + d2);
      Vt[d2][kv] = (unsigned short)(vv & 0xffffu);
      Vt[d2 + 1][kv] = (unsigned short)(vv >> 16);
    }
  }

  int c16 = lane & 15, g4 = lane >> 4;

  int qrow = q0 + c16; if (qrow > T_ - 1) qrow = T_ - 1;
  bf16x8 aq[2];
#pragma unroll
  for (int ks = 0; ks < 2; ++ks)
    aq[ks] = *(const bf16x8*)(base + (size_t)qrow * (3 * D_) + ks * 32 + g4 * 8);

  f32x4 sc[14];
#pragma unroll
  for (int nf = 0; nf < 14; ++nf) sc[nf] = (f32x4){0.f, 0.f, 0.f, 0.f};
  const unsigned short* kb = base + D_;
#pragma unroll
  for (int nf = 0; nf < 14; ++nf) {
    int krow = nf * 16 + c16; if (krow > T_ - 1) krow = T_ - 1;
#pragma unroll
    for (int ks = 0; ks < 2; ++ks) {
      bf16x8 bk = *(const bf16x8*)(kb + (size_t)krow * (3 * D_) + ks * 32 + g4 * 8);
      sc[nf] = __builtin_amdgcn_mfma_f32_16x16x32_bf16(aq[ks], bk, sc[nf], 0, 0, 0);
    }
  }

  float mx[4], sm[4];
#pragma unroll
  for (int r = 0; r < 4; ++r) mx[r] = -1e30f;
#pragma unroll
  for (int nf = 0; nf < 14; ++nf) {
    bool valid = (nf * 16 + c16) < T_;
#pragma unroll
    for (int r = 0; r < 4; ++r) {
      float s = valid ? sc[nf][r] * 0.125f : -1e30f;
      sc[nf][r] = s;
      mx[r] = fmaxf(mx[r], s);
    }
  }
#pragma unroll
  for (int r = 0; r < 4; ++r) {
#pragma unroll
    for (int off = 1; off < 16; off <<= 1) mx[r] = fmaxf(mx[r], __shfl_xor(mx[r], off, 16));
    sm[r] = 0.f;
  }
#pragma unroll
  for (int nf = 0; nf < 14; ++nf)
#pragma unroll
    for (int r = 0; r < 4; ++r) {
      float p = __expf(sc[nf][r] - mx[r]);
      sc[nf][r] = p;
      sm[r] += p;
    }
#pragma unroll
  for (int r = 0; r < 4; ++r) {
#pragma unroll
    for (int off = 1; off < 16; off <<= 1) sm[r] += __shfl_xor(sm[r], off, 16);
    sm[r] = 1.f / sm[r];
  }
#pragma unroll
  for (int nf = 0; nf < 14; ++nf) {
    int col = nf * 16 + c16;
#pragma unroll
    for (int r = 0; r < 4; ++r)
      Pl[w][g4 * 4 + r][col] = f2bf(sc[nf][r] * sm[r]);
  }
  __syncthreads();

  f32x4 oacc[4];
#pragma unroll
  for (int nf = 0; nf < 4; ++nf) oacc[nf] = (f32x4){0.f, 0.f, 0.f, 0.f};
#pragma unroll
  for (int ks = 0; ks < 7; ++ks) {
    bf16x8 ap = *(const bf16x8*)&Pl[w][c16][ks * 32 + g4 * 8];
#pragma unroll
    for (int nf = 0; nf < 4; ++nf) {
      bf16x8 bv = *(const bf16x8*)&Vt[nf * 16 + c16][ks * 32 + g4 * 8];
      oacc[nf] = __builtin_amdgcn_mfma_f32_16x16x32_bf16(ap, bv, oacc[nf], 0, 0, 0);
    }
  }

#pragma unroll
  for (int nf = 0; nf < 4; ++nf) {
    int d = nf * 16 + c16;
#pragma unroll
    for (int r = 0; r < 4; ++r) {
      int q = q0 + g4 * 4 + r;
      if (q < T_)
        ob[((size_t)b * T_ + q) * D_ + h * HD_ + d] = f2bf(oacc[nf][r]);
    }
  }
}

// ---------------- final LN(row 0) + head ----------------
__global__ void head_kernel(const float* __restrict__ t, const float* __restrict__ nw,
                            const float* __restrict__ nb, const float* __restrict__ hw,
                            const float* __restrict__ hb, const int* __restrict__ idx,
                            float* __restrict__ out) {
  int b = blockIdx.x;
  int e = idx[b];
  int lane = threadIdx.x;  // 64
  const float* rp = t + (size_t)b * T_ * D_;
  float v[6];
  float s = 0.f;
#pragma unroll
  for (int j = 0; j < 6; ++j) { v[j] = rp[lane + j * 64]; s += v[j]; }
#pragma unroll
  for (int off = 1; off < 64; off <<= 1) s += __shfl_xor(s, off);
  float mean = s * (1.f / 384.f);
  float sq = 0.f;
#pragma unroll
  for (int j = 0; j < 6; ++j) { float dd = v[j] - mean; sq += dd * dd; }
#pragma unroll
  for (int off = 1; off < 64; off <<= 1) sq += __shfl_xor(sq, off);
  float rs = rsqrtf(sq * (1.f / 384.f) + 1e-6f);
  __shared__ float ln[D_];
#pragma unroll
  for (int j = 0; j < 6; ++j) {
    int d = lane + j * 64;
    ln[d] = (v[j] - mean) * rs * nw[e * D_ + d] + nb[e * D_ + d];
  }
  __syncthreads();
  if (lane < NC_) {
    float acc = hb[e * NC_ + lane];
    for (int d = 0; d < D_; ++d) acc += ln[d] * hw[((size_t)e * D_ + d) * NC_ + lane];
    out[b * NC_ + lane] = acc;
  }
}

extern "C" void kernel_launch(void* const* d_in, const int* in_sizes, int n_in,
                              void* d_out, int out_size, void* d_ws, size_t ws_size,
                              hipStream_t stream) {
  const float* x      = (const float*)d_in[0];
  const float* gate_w = (const float*)d_in[1];
  const float* gate_b = (const float*)d_in[2];
  const float* patch_w = (const float*)d_in[3];
  const float* patch_b = (const float*)d_in[4];
  const float* cls    = (const float*)d_in[5];
  const float* pos    = (const float*)d_in[6];
  const float* ln1_w  = (const float*)d_in[7];
  const float* ln1_b  = (const float*)d_in[8];
  const float* qkv_w  = (const float*)d_in[9];
  const float* qkv_b  = (const float*)d_in[10];
  const float* proj_w = (const float*)d_in[11];
  const float* proj_b = (const float*)d_in[12];
  const float* ln2_w  = (const float*)d_in[13];
  const float* ln2_b  = (const float*)d_in[14];
  const float* fc1_w  = (const float*)d_in[15];
  const float* fc1_b  = (const float*)d_in[16];
  const float* fc2_w  = (const float*)d_in[17];
  const float* fc2_b  = (const float*)d_in[18];
  const float* norm_w = (const float*)d_in[19];
  const float* norm_b = (const float*)d_in[20];
  const float* head_w = (const float*)d_in[21];
  const float* head_b = (const float*)d_in[22];

  const size_t SQ = (size_t)D_ * 3 * D_, SP = (size_t)D_ * D_;
  const size_t S1 = (size_t)D_ * FF_, S2 = (size_t)FF_ * D_;
  const size_t WSET = SQ + SP + S1 + S2;

  float* ws = (float*)d_ws;
  int* idx = (int*)ws;                                   // 64 slots
  float4* gpart = (float4*)(ws + 64);                    // B*GSPLIT float4 = 2048 floats
  float* t = ws + 64 + 4 * B_ * GSPLIT;                  // B*T*D f32
  unsigned short* qkvb = (unsigned short*)(t + (size_t)B_ * T_ * D_);
  unsigned short* hb = qkvb + (size_t)B_ * T_ * 3 * D_;
  unsigned short* ob = hb + (size_t)B_ * T_ * D_;
  unsigned short* ub = ob + (size_t)B_ * T_ * D_;
  unsigned short* wbase = ub + (size_t)B_ * T_ * FF_;
  size_t fixed_bytes = (size_t)((char*)wbase - (char*)d_ws);
  bool hoist = ws_size >= fixed_bytes + WSET * 2ull * E_ * L_ + 4096;
  int NL = hoist ? L_ : 1;
  unsigned short* tq = wbase;
  unsigned short* tp = tq + (size_t)NL * E_ * SQ;
  unsigned short* t1 = tp + (size_t)NL * E_ * SP;
  unsigned short* t2 = t1 + (size_t)NL * E_ * S1;

  gate_partial<<<dim3(B_, GSPLIT), 256, 0, stream>>>(x, gate_w, gpart);
  gate_reduce<<<B_, 64, 0, stream>>>(gpart, gate_b, idx);
  cls_kernel<<<B_, D_, 0, stream>>>(cls, pos, idx, t);
  patch_kernel<<<dim3(14, B_), D_, 0, stream>>>(x, patch_w, patch_b, pos, idx, t);
  if (hoist)
    wtrans_kernel<<<dim3(1728, E_, L_), 256, 0, stream>>>(qkv_w, proj_w, fc1_w, fc2_w,
                                                          tq, tp, t1, t2, 0);
  for (int l = 0; l < L_; ++l) {
    int slot = hoist ? l : 0;
    if (!hoist)
      wtrans_kernel<<<dim3(1728, E_, 1), 256, 0, stream>>>(qkv_w, proj_w, fc1_w, fc2_w,
                                                           tq, tp, t1, t2, l);
    unsigned short* tql = tq + (size_t)slot * E_ * SQ;
    unsigned short* tpl = tp + (size_t)slot * E_ * SP;
    unsigned short* t1l = t1 + (size_t)slot * E_ * S1;
    unsigned short* t2l = t2 + (size_t)slot * E_ * S2;
    ln_kernel<<<dim3(50, B_), 256, 0, stream>>>(t, hb, ln1_w, ln1_b, idx, l);
    gemm_mfma<3><<<dim3(9, 4, B_), 256, 0, stream>>>(hb, tql, qkv_b, qkvb, idx, l, D_, 3 * D_);
    attn_mfma<<<dim3(7, H_, B_), 128, 0, stream>>>(qkvb, ob);
    gemm_mfma<1><<<dim3(3, 4, B_), 256, 0, stream>>>(ob, tpl, proj_b, t, idx, l, D_, D_);
    ln_kernel<<<dim3(50, B_), 256, 0, stream>>>(t, hb, ln2_w, ln2_b, idx, l);
    gemm_mfma<2><<<dim3(12, 4, B_), 256, 0, stream>>>(hb, t1l, fc1_b, ub, idx, l, D_, FF_);
    gemm_mfma<1><<<dim3(3, 4, B_), 256, 0, stream>>>(ub, t2l, fc2_b, t, idx, l, FF_, D_);
  }
  head_kernel<<<B_, 64, 0, stream>>>(t, norm_w, norm_b, head_w, head_b, idx, (float*)d_out);
}